// Round 1
// 765.804 us; speedup vs baseline: 1.1600x; 1.1600x over previous
//
#include <hip/hip_runtime.h>

// Problem constants (fixed by the reference setup)
#define NE     50000   // edges
#define KMAX   16
#define NSPH   16
#define EMB    64
#define INTERM 64
#define UOUT   128

// R1: 32 edges/block (was 64). Per-wave state halves: Sfrag 32 VGPR, Arbf 8,
// Oacc 8 -> fits the 128-VGPR cap of __launch_bounds__(512,4) WITHOUT scratch
// spill (previous version spilled ~400 MB/dispatch each way: WRITE_SIZE 434 MB
// vs 26 MB legitimate).
#define EPB    32      // edges per block
#define LPW    4       // edges per wave (8 waves)

typedef __attribute__((ext_vector_type(4))) float v4f;
typedef __attribute__((ext_vector_type(4))) short s4;
typedef __attribute__((ext_vector_type(8))) short s8;

__device__ inline unsigned short f2b(float x){
  union { float f; unsigned int u; } v; v.f = x;
  unsigned int r = v.u + 0x7FFFu + ((v.u >> 16) & 1u);   // RNE f32->bf16
  return (unsigned short)(r >> 16);
}

__device__ inline s4 cvt4(v4f v){
  s4 r;
  r.x = (short)f2b(v.x); r.y = (short)f2b(v.y);
  r.z = (short)f2b(v.z); r.w = (short)f2b(v.w);
  return r;
}

// ---- prep kernel 1: scatter (id_reduce, Kidx) -> slot map (edge*16+slot -> triplet or -1)
__global__ void scatter_map_kernel(const int* __restrict__ idr, const int* __restrict__ kidx,
                                   int* __restrict__ map, int n){
  int t = blockIdx.x * 256 + threadIdx.x;
  if (t < n) map[idr[t] * KMAX + kidx[t]] = t;
}

// ---- prep kernel 2: pack f32 weight[c][i][u] into bf16 MFMA-B layout Wb[k>>3][u][k&7]
// k = ic*1024 + hf*512 + il*32 + chalf,  i = ic*16+il, c = hf*32+chalf
__global__ void pack_w_kernel(const float* __restrict__ wgt, unsigned short* __restrict__ wb){
  int o = blockIdx.x * 256 + threadIdx.x;          // 64*64*128 = 524288 total
  int j  = o & 7;
  int rest = o >> 3;
  int u  = rest & 127;
  int kb = rest >> 7;
  int k  = kb * 8 + j;
  int ic = k >> 10, rem = k & 1023, hf = rem >> 9, r2 = rem & 511, il = r2 >> 5, ch = r2 & 31;
  int i = ic * 16 + il, c = hf * 32 + ch;
  wb[o] = f2b(wgt[c * (INTERM * UOUT) + i * UOUT + u]);
}

// ---- fused kernel: 32 edges/block, 8 waves. S in regs (C-layout==B-layout for K=16 MFMA),
// T goes MFMA -> (cvt) -> swizzled LDS directly, rbf A-frags cached per i-chunk,
// out accumulates in VGPRs. All fragment layouts identical to the 64-edge version.
__global__ __launch_bounds__(512, 4)   // cap VGPR at 128, 2 blocks/CU
void fused_kernel(const float* __restrict__ rbf,
                  const float* __restrict__ sph,
                  const float* __restrict__ m,
                  const unsigned short* __restrict__ wb,
                  const int* __restrict__ map,
                  float* __restrict__ out)
{
  __shared__ __align__(16) unsigned short Tlds[EPB * 512];   // 32 KB
  const int tid = threadIdx.x;
  const int l = tid & 63;
  const int w = tid >> 6;       // wave 0..7
  const int q = l >> 4;         // quad 0..3
  const int h = l & 15;
  const int ebase = blockIdx.x * EPB;

  // ---------- phase 0: S = sph @ m2 for this wave's 4 edges; keep as B-frags (K=16) in regs
  s4 Sfrag[LPW][4];
#pragma unroll
  for (int le = 0; le < LPW; ++le){
    int e = ebase + w * LPW + le; if (e >= NE) e = NE - 1;
    // A-frag (sph): A[s=h][k=q*4+j] -> 16B contiguous f32 load, convert
    s4 a = cvt4(*reinterpret_cast<const v4f*>(sph + e * 256 + h * 16 + q * 4));
    int t0 = map[e * 16 + q * 4 + 0];
    int t1 = map[e * 16 + q * 4 + 1];
    int t2 = map[e * 16 + q * 4 + 2];
    int t3 = map[e * 16 + q * 4 + 3];
#pragma unroll
    for (int ct = 0; ct < 4; ++ct){
      int c = ct * 16 + h;
      // B-frag (m2 gather): B[k=q*4+j][n=c]
      s4 b;
      b.x = (t0 >= 0) ? (short)f2b(m[t0 * 64 + c]) : (short)0;
      b.y = (t1 >= 0) ? (short)f2b(m[t1 * 64 + c]) : (short)0;
      b.z = (t2 >= 0) ? (short)f2b(m[t2 * 64 + c]) : (short)0;
      b.w = (t3 >= 0) ? (short)f2b(m[t3 * 64 + c]) : (short)0;
      v4f acc = {0.f, 0.f, 0.f, 0.f};
      acc = __builtin_amdgcn_mfma_f32_16x16x16bf16_1k(a, b, acc, 0, 0, 0);
      // D[s=q*4+r][c=h] == B-frag[k=q*4+j][n=h]  -> direct reuse as next B operand
      Sfrag[le][ct] = cvt4(acc);
    }
  }

  v4f Oacc[2];
#pragma unroll
  for (int mt = 0; mt < 2; ++mt) Oacc[mt] = (v4f){0.f, 0.f, 0.f, 0.f};

#pragma unroll 1   // keep i-chunk loop rolled: I-cache
  for (int ic = 0; ic < 4; ++ic){
    // rbf A-frags for this i-chunk, cached across both hf passes (8 VGPRs)
    s4 Arbf[LPW];
#pragma unroll
    for (int le = 0; le < LPW; ++le){
      int e = ebase + w * LPW + le; if (e >= NE) e = NE - 1;
      Arbf[le] = cvt4(*reinterpret_cast<const v4f*>(rbf + e * 1024 + (ic * 16 + h) * 16 + q * 4));
    }
#pragma unroll
    for (int hf = 0; hf < 2; ++hf){
      // ---------- step 2+write: T[il][c-half] -> MFMA -> cvt -> swizzled LDS, no register block
#pragma unroll
      for (int le = 0; le < LPW; ++le){
        int row = w * LPW + le;
#pragma unroll
        for (int ct2 = 0; ct2 < 2; ++ct2){
          v4f acc = {0.f, 0.f, 0.f, 0.f};
          acc = __builtin_amdgcn_mfma_f32_16x16x16bf16_1k(Arbf[le], Sfrag[le][hf * 2 + ct2], acc, 0, 0, 0);
          s4 tv = cvt4(acc);   // T[il=q*4+r][c=(hf*2+ct2)*16+h]
#pragma unroll
          for (int r = 0; r < 4; ++r){
            int il = q * 4 + r;
            int kh = il * 32 + ct2 * 16 + h;
            int b  = kh >> 3;
            int bs = b ^ (row & 7) ^ (((b >> 4) & 3) << 1);
            Tlds[row * 512 + bs * 8 + (kh & 7)] = (unsigned short)tv[r];
          }
        }
      }
      __syncthreads();
      // ---------- step 3: out += T_half(32x512) @ Wb(512x128)
      const int kbase = ic * 1024 + hf * 512;
#pragma unroll
      for (int ks = 0; ks < 16; ++ks){
        int k0 = ks * 32;
        int bb = (k0 >> 3) + q;
        int bsw = bb ^ (h & 7) ^ (((bb >> 4) & 3) << 1);   // same for all mt (mt*16 % 8 == 0)
        // B-frag: B[k=q*8+j][u=w*16+h] from packed Wb
        int kb = (kbase + k0 + q * 8) >> 3;
        s8 bfr = *reinterpret_cast<const s8*>(wb + (kb * 128 + (w * 16 + h)) * 8);
#pragma unroll
        for (int mt = 0; mt < 2; ++mt){
          int row = mt * 16 + h;   // A-frag: A[edge=h][k contiguous 8]
          s8 afr = *reinterpret_cast<const s8*>(&Tlds[row * 512 + bsw * 8]);
          Oacc[mt] = __builtin_amdgcn_mfma_f32_16x16x32_bf16(afr, bfr, Oacc[mt], 0, 0, 0);
        }
      }
      __syncthreads();
    }
  }

  // ---------- epilogue: D[edge=q*4+r (within 16)][u=h], u-block = w*16; f32 out
#pragma unroll
  for (int mt = 0; mt < 2; ++mt){
#pragma unroll
    for (int r = 0; r < 4; ++r){
      int e = ebase + mt * 16 + q * 4 + r;
      if (e < NE) out[e * 128 + w * 16 + h] = Oacc[mt][r];
    }
  }
}

extern "C" void kernel_launch(void* const* d_in, const int* in_sizes, int n_in,
                              void* d_out, int out_size, void* d_ws, size_t ws_size,
                              hipStream_t stream) {
  const float* rbf = (const float*)d_in[0];   // (NE, 64, 16) f32
  const float* sph = (const float*)d_in[1];   // (NE, 16, 16) f32
  const float* m   = (const float*)d_in[2];   // (400000, 64) f32
  const float* wgt = (const float*)d_in[3];   // (64, 64, 128) f32
  const int* idr  = (const int*)d_in[4];      // (400000,) int32
  const int* kidx = (const int*)d_in[5];      // (400000,) int32
  float* out = (float*)d_out;                 // (NE, 128) f32

  const int nTrip = in_sizes[4];
  int*            map = (int*)d_ws;                                   // NE*16 int32 = 3.2 MB
  unsigned short* wb  = (unsigned short*)((char*)d_ws + (size_t)NE * 16 * 4); // 1 MB packed bf16 weight

  hipMemsetAsync(map, 0xFF, (size_t)NE * 16 * 4, stream);             // all slots -> -1
  scatter_map_kernel<<<dim3((nTrip + 255) / 256), dim3(256), 0, stream>>>(idr, kidx, map, nTrip);
  pack_w_kernel<<<dim3((EMB * INTERM * UOUT) / 256), dim3(256), 0, stream>>>(wgt, wb);
  fused_kernel<<<dim3((NE + EPB - 1) / EPB), dim3(512), 0, stream>>>(rbf, sph, m, wb, map, out);
}

// Round 2
// 619.359 us; speedup vs baseline: 1.4343x; 1.2364x over previous
//
#include <hip/hip_runtime.h>

// Problem constants (fixed by the reference setup)
#define NE     50000   // edges
#define KMAX   16
#define NSPH   16
#define EMB    64
#define INTERM 64
#define UOUT   128

// R1: 32 edges/block. R2: cap ks-loop unroll at 4 — the fully-unrolled (16x)
// ks loop let the scheduler hoist 16 in-flight bfr global loads (64 VGPRs),
// blowing the 128-VGPR budget and spilling Sfrag to scratch every (ic,hf)
// pass (~185 MB/dispatch round-trip: WRITE_SIZE 209 MB vs 26 MB legitimate).
#define EPB    32      // edges per block
#define LPW    4       // edges per wave (8 waves)

typedef __attribute__((ext_vector_type(4))) float v4f;
typedef __attribute__((ext_vector_type(4))) short s4;
typedef __attribute__((ext_vector_type(8))) short s8;

__device__ inline unsigned short f2b(float x){
  union { float f; unsigned int u; } v; v.f = x;
  unsigned int r = v.u + 0x7FFFu + ((v.u >> 16) & 1u);   // RNE f32->bf16
  return (unsigned short)(r >> 16);
}

__device__ inline s4 cvt4(v4f v){
  s4 r;
  r.x = (short)f2b(v.x); r.y = (short)f2b(v.y);
  r.z = (short)f2b(v.z); r.w = (short)f2b(v.w);
  return r;
}

// ---- prep kernel 1: scatter (id_reduce, Kidx) -> slot map (edge*16+slot -> triplet or -1)
__global__ void scatter_map_kernel(const int* __restrict__ idr, const int* __restrict__ kidx,
                                   int* __restrict__ map, int n){
  int t = blockIdx.x * 256 + threadIdx.x;
  if (t < n) map[idr[t] * KMAX + kidx[t]] = t;
}

// ---- prep kernel 2: pack f32 weight[c][i][u] into bf16 MFMA-B layout Wb[k>>3][u][k&7]
// k = ic*1024 + hf*512 + il*32 + chalf,  i = ic*16+il, c = hf*32+chalf
__global__ void pack_w_kernel(const float* __restrict__ wgt, unsigned short* __restrict__ wb){
  int o = blockIdx.x * 256 + threadIdx.x;          // 64*64*128 = 524288 total
  int j  = o & 7;
  int rest = o >> 3;
  int u  = rest & 127;
  int kb = rest >> 7;
  int k  = kb * 8 + j;
  int ic = k >> 10, rem = k & 1023, hf = rem >> 9, r2 = rem & 511, il = r2 >> 5, ch = r2 & 31;
  int i = ic * 16 + il, c = hf * 32 + ch;
  wb[o] = f2b(wgt[c * (INTERM * UOUT) + i * UOUT + u]);
}

// ---- fused kernel: 32 edges/block, 8 waves. S in regs (C-layout==B-layout for K=16 MFMA),
// T goes MFMA -> (cvt) -> swizzled LDS directly, rbf A-frags cached per i-chunk,
// out accumulates in VGPRs. All fragment layouts identical to the 64-edge version.
__global__ __launch_bounds__(512, 4)   // cap VGPR at 128, 2 blocks/CU
void fused_kernel(const float* __restrict__ rbf,
                  const float* __restrict__ sph,
                  const float* __restrict__ m,
                  const unsigned short* __restrict__ wb,
                  const int* __restrict__ map,
                  float* __restrict__ out)
{
  __shared__ __align__(16) unsigned short Tlds[EPB * 512];   // 32 KB
  const int tid = threadIdx.x;
  const int l = tid & 63;
  const int w = tid >> 6;       // wave 0..7
  const int q = l >> 4;         // quad 0..3
  const int h = l & 15;
  const int ebase = blockIdx.x * EPB;

  // ---------- phase 0: S = sph @ m2 for this wave's 4 edges; keep as B-frags (K=16) in regs
  s4 Sfrag[LPW][4];
#pragma unroll
  for (int le = 0; le < LPW; ++le){
    int e = ebase + w * LPW + le; if (e >= NE) e = NE - 1;
    // A-frag (sph): A[s=h][k=q*4+j] -> 16B contiguous f32 load, convert
    s4 a = cvt4(*reinterpret_cast<const v4f*>(sph + e * 256 + h * 16 + q * 4));
    int t0 = map[e * 16 + q * 4 + 0];
    int t1 = map[e * 16 + q * 4 + 1];
    int t2 = map[e * 16 + q * 4 + 2];
    int t3 = map[e * 16 + q * 4 + 3];
#pragma unroll
    for (int ct = 0; ct < 4; ++ct){
      int c = ct * 16 + h;
      // B-frag (m2 gather): B[k=q*4+j][n=c]
      s4 b;
      b.x = (t0 >= 0) ? (short)f2b(m[t0 * 64 + c]) : (short)0;
      b.y = (t1 >= 0) ? (short)f2b(m[t1 * 64 + c]) : (short)0;
      b.z = (t2 >= 0) ? (short)f2b(m[t2 * 64 + c]) : (short)0;
      b.w = (t3 >= 0) ? (short)f2b(m[t3 * 64 + c]) : (short)0;
      v4f acc = {0.f, 0.f, 0.f, 0.f};
      acc = __builtin_amdgcn_mfma_f32_16x16x16bf16_1k(a, b, acc, 0, 0, 0);
      // D[s=q*4+r][c=h] == B-frag[k=q*4+j][n=h]  -> direct reuse as next B operand
      Sfrag[le][ct] = cvt4(acc);
    }
  }

  v4f Oacc[2];
#pragma unroll
  for (int mt = 0; mt < 2; ++mt) Oacc[mt] = (v4f){0.f, 0.f, 0.f, 0.f};

#pragma unroll 1   // keep i-chunk loop rolled: I-cache
  for (int ic = 0; ic < 4; ++ic){
    // rbf A-frags for this i-chunk, cached across both hf passes (8 VGPRs)
    s4 Arbf[LPW];
#pragma unroll
    for (int le = 0; le < LPW; ++le){
      int e = ebase + w * LPW + le; if (e >= NE) e = NE - 1;
      Arbf[le] = cvt4(*reinterpret_cast<const v4f*>(rbf + e * 1024 + (ic * 16 + h) * 16 + q * 4));
    }
#pragma unroll
    for (int hf = 0; hf < 2; ++hf){
      // ---------- step 2+write: T[il][c-half] -> MFMA -> cvt -> swizzled LDS, no register block
#pragma unroll
      for (int le = 0; le < LPW; ++le){
        int row = w * LPW + le;
#pragma unroll
        for (int ct2 = 0; ct2 < 2; ++ct2){
          v4f acc = {0.f, 0.f, 0.f, 0.f};
          acc = __builtin_amdgcn_mfma_f32_16x16x16bf16_1k(Arbf[le], Sfrag[le][hf * 2 + ct2], acc, 0, 0, 0);
          s4 tv = cvt4(acc);   // T[il=q*4+r][c=(hf*2+ct2)*16+h]
#pragma unroll
          for (int r = 0; r < 4; ++r){
            int il = q * 4 + r;
            int kh = il * 32 + ct2 * 16 + h;
            int b  = kh >> 3;
            int bs = b ^ (row & 7) ^ (((b >> 4) & 3) << 1);
            Tlds[row * 512 + bs * 8 + (kh & 7)] = (unsigned short)tv[r];
          }
        }
      }
      __syncthreads();
      // ---------- step 3: out += T_half(32x512) @ Wb(512x128)
      // R2: unroll capped at 4 so only 4 bfr (16 VGPRs) are in flight at the
      // scheduling peak, instead of 16 (64 VGPRs) -> no Sfrag spill.
      const int kbase = ic * 1024 + hf * 512;
#pragma unroll 4
      for (int ks = 0; ks < 16; ++ks){
        int k0 = ks * 32;
        int bb = (k0 >> 3) + q;
        int bsw = bb ^ (h & 7) ^ (((bb >> 4) & 3) << 1);   // same for all mt (mt*16 % 8 == 0)
        // B-frag: B[k=q*8+j][u=w*16+h] from packed Wb
        int kb = (kbase + k0 + q * 8) >> 3;
        s8 bfr = *reinterpret_cast<const s8*>(wb + (kb * 128 + (w * 16 + h)) * 8);
#pragma unroll
        for (int mt = 0; mt < 2; ++mt){
          int row = mt * 16 + h;   // A-frag: A[edge=h][k contiguous 8]
          s8 afr = *reinterpret_cast<const s8*>(&Tlds[row * 512 + bsw * 8]);
          Oacc[mt] = __builtin_amdgcn_mfma_f32_16x16x32_bf16(afr, bfr, Oacc[mt], 0, 0, 0);
        }
      }
      __syncthreads();
    }
  }

  // ---------- epilogue: D[edge=q*4+r (within 16)][u=h], u-block = w*16; f32 out
#pragma unroll
  for (int mt = 0; mt < 2; ++mt){
#pragma unroll
    for (int r = 0; r < 4; ++r){
      int e = ebase + mt * 16 + q * 4 + r;
      if (e < NE) out[e * 128 + w * 16 + h] = Oacc[mt][r];
    }
  }
}

extern "C" void kernel_launch(void* const* d_in, const int* in_sizes, int n_in,
                              void* d_out, int out_size, void* d_ws, size_t ws_size,
                              hipStream_t stream) {
  const float* rbf = (const float*)d_in[0];   // (NE, 64, 16) f32
  const float* sph = (const float*)d_in[1];   // (NE, 16, 16) f32
  const float* m   = (const float*)d_in[2];   // (400000, 64) f32
  const float* wgt = (const float*)d_in[3];   // (64, 64, 128) f32
  const int* idr  = (const int*)d_in[4];      // (400000,) int32
  const int* kidx = (const int*)d_in[5];      // (400000,) int32
  float* out = (float*)d_out;                 // (NE, 128) f32

  const int nTrip = in_sizes[4];
  int*            map = (int*)d_ws;                                   // NE*16 int32 = 3.2 MB
  unsigned short* wb  = (unsigned short*)((char*)d_ws + (size_t)NE * 16 * 4); // 1 MB packed bf16 weight

  hipMemsetAsync(map, 0xFF, (size_t)NE * 16 * 4, stream);             // all slots -> -1
  scatter_map_kernel<<<dim3((nTrip + 255) / 256), dim3(256), 0, stream>>>(idr, kidx, map, nTrip);
  pack_w_kernel<<<dim3((EMB * INTERM * UOUT) / 256), dim3(256), 0, stream>>>(wgt, wb);
  fused_kernel<<<dim3((NE + EPB - 1) / EPB), dim3(512), 0, stream>>>(rbf, sph, m, wb, map, out);
}